// Round 1
// 298.112 us; speedup vs baseline: 1.0172x; 1.0172x over previous
//
#include <hip/hip_runtime.h>
#include <hip/hip_bf16.h>
#include <stdint.h>
#include <math.h>

// Problem constants
#define DD 1024
#define SS 2048
#define BB 4

typedef __bf16 bf16;
typedef __bf16 bf16x8 __attribute__((ext_vector_type(8)));
typedef __bf16 bf16x4 __attribute__((ext_vector_type(4)));
typedef float f32x4 __attribute__((ext_vector_type(4)));

// ---- async global->LDS 16B copy (dest = wave-uniform base + lane*16) ----
__device__ __forceinline__ void gload_lds16(const bf16* g, bf16* l) {
  __builtin_amdgcn_global_load_lds(
      (const __attribute__((address_space(1))) void*)g,
      (__attribute__((address_space(3))) void*)l, 16, 0, 0);
}

// ---- ALL preprocessing in ONE dispatch --------------------------------
// blocks [0,11264):     fp32->bf16 cvt of x, R, E, Wv
// blocks [11264,13312): transpose+cvt Wq -> WqT, Wk -> WkT
// blocks [13312,16384): bias fold (R@bq | E@bk | bv)
// blocks [16384,16416): zero rowsums (8192 floats)
__global__ __launch_bounds__(256) void prep_all(
    const float* __restrict__ x, const float* __restrict__ R,
    const float* __restrict__ E, const float* __restrict__ Wv,
    const float* __restrict__ Wq, const float* __restrict__ Wk,
    const float* __restrict__ bq, const float* __restrict__ bk,
    const float* __restrict__ bv, bf16* __restrict__ xb,
    bf16* __restrict__ Rb, bf16* __restrict__ Eb, bf16* __restrict__ Wvb,
    bf16* __restrict__ WqT, bf16* __restrict__ WkT, float* __restrict__ bias,
    float* __restrict__ rowsums) {
  int bid = blockIdx.x;
  int t = threadIdx.x;
  if (bid < 11264) {
    const float* src;
    bf16* dst;
    int base;
    if (bid < 8192) { src = x; dst = xb; base = bid; }
    else if (bid < 9216) { src = R; dst = Rb; base = bid - 8192; }
    else if (bid < 10240) { src = E; dst = Eb; base = bid - 9216; }
    else { src = Wv; dst = Wvb; base = bid - 10240; }
    int i = (base * 256 + t) * 4;
    float4 v = *(const float4*)(src + i);
    bf16x4 o;
    o.x = (bf16)v.x; o.y = (bf16)v.y; o.z = (bf16)v.z; o.w = (bf16)v.w;
    *(bf16x4*)(dst + i) = o;
  } else if (bid < 13312) {
    int r2 = bid - 11264;
    const float* src = (r2 >= 1024) ? Wk : Wq;
    bf16* dst = (r2 >= 1024) ? WkT : WqT;
    int rem = r2 & 1023;
    int bx = rem & 31, by = rem >> 5;
    __shared__ float tile[32][33];
    int tx = t & 31, ty = t >> 5;
    int xcol = bx * 32 + tx;
    int y0 = by * 32;
    for (int r = ty; r < 32; r += 8)
      tile[r][tx] = src[(y0 + r) * DD + xcol];
    __syncthreads();
    int dx = by * 32 + tx;
    int dy0 = bx * 32;
    for (int r = ty; r < 32; r += 8)
      dst[(dy0 + r) * DD + dx] = (bf16)tile[tx][r];
  } else if (bid < 16384) {
    int e = bid - 13312;  // 0..3071
    if (e >= 2048) { if (t == 0) bias[e] = bv[e - 2048]; return; }
    const float* M = (e < 1024) ? R : E;
    const float* bb = (e < 1024) ? bq : bk;
    int row = e & 1023;
    float s = 0.f;
    for (int f = t; f < DD; f += 256) s += M[row * DD + f] * bb[f];
    for (int o = 32; o >= 1; o >>= 1) s += __shfl_xor(s, o, 64);
    __shared__ float red[4];
    if ((t & 63) == 0) red[t >> 6] = s;
    __syncthreads();
    if (t == 0) bias[e] = red[0] + red[1] + red[2] + red[3];
  } else {
    int idx = (bid - 16384) * 256 + t;  // 0..8191
    rowsums[idx] = 0.f;
  }
}

// ---- generic bf16 GEMM: C = scale * (A @ B^T) (+bias), 128x128 tiles ----
// K-loop: depth-1 prefetch pipeline, 32-wide K steps, double-buffered in the
// SAME 32KB LDS (two 128x32 halves per matrix) so occupancy stays 4 blk/CU.
// Raw s_barrier + counted waits (NO __syncthreads in the loop -> prefetch
// global_load_lds stays in flight across the barrier; the vmcnt(0) at the
// top of each iter waits for loads issued one full MFMA phase earlier).
// MODE 0: C bf16 (+bias). If vTp set and n0>=2048 (QKV V-region), the tile is
//         written TRANSPOSED to vT[b][d][s] via an XOR-swizzled LDS bounce.
// MODE 1: causal scores with FUSED EXP: dense triangular grid (blockIdx.x
//         decodes to (bx<=by)); P~ = exp(scale*acc) (0 above diag) written as
//         bf16 via swizzled LDS bounce (vectorized); per-row sums of the
//         bf16-rounded P~ atomically added to rowsums[b*SS+row].
// MODE 2: P~ @ V with K truncated at (by+1)*128, by reversed (long-first);
//         epilogue divides by rowsums (softmax normalization folded here).
template <int MODE>
__global__ __launch_bounds__(256, 4)
void gemm_bt(const bf16* __restrict__ Ag, long lda, long sAb,
             const bf16* __restrict__ Bg, long ldb, long sBb,
             void* __restrict__ Cg, long ldc, long sCb,
             const float* __restrict__ bias, float scale, int K,
             bf16* __restrict__ vTp, float* __restrict__ rowsums) {
  __shared__ __align__(16) bf16 smem[16384];  // As | Bs ; reused for bounce
  bf16* As = smem;
  bf16* Bs = smem + 8192;

  int bx = blockIdx.x, by = blockIdx.y, bz = blockIdx.z;
  if (MODE == 0 || MODE == 1) {
    // bijective XCD-chunk swizzle (m204 formula): each XCD gets a contiguous
    // chunk of the grid -> neighboring tiles share A-strip/B-panel in its L2.
    int nx = (int)gridDim.x;
    int nwg = nx * (int)gridDim.y;
    int id = by * nx + bx;
    int xcd = id & 7, rest = id >> 3;
    int q8 = nwg >> 3, r8 = nwg & 7;
    int wg = (xcd < r8 ? xcd * (q8 + 1) : r8 * (q8 + 1) + (xcd - r8) * q8)
             + rest;
    bx = wg % nx;
    by = wg / nx;
  }
  if (MODE == 1) {  // triangular decode: q -> (by, bx<=by)
    int q = bx;
    by = (int)((sqrtf(8.f * q + 1.f) - 1.f) * 0.5f);
    while ((by + 1) * (by + 2) / 2 <= q) by++;
    while (by * (by + 1) / 2 > q) by--;
    bx = q - by * (by + 1) / 2;
  }
  if (MODE == 2) by = 15 - by;  // longest K strips dispatch first
  long m0 = (long)by * 128, n0 = (long)bx * 128;
  const bf16* A = Ag + (long)bz * sAb + m0 * lda;
  const bf16* Bp = Bg + (long)bz * sBb + n0 * ldb;

  int t = threadIdx.x;
  int w = t >> 6, l = t & 63;
  int lr = l >> 2;
  int lc = (((l & 3) ^ (lr & 3)) * 8);  // swizzled source chunk
  int quad = l >> 4, ln = l & 15;
  int wm = w >> 1, wn = w & 1;
  int rdoff = ((quad ^ (ln & 3)) * 8);  // swizzled read offset

  int Keff = (MODE == 2) ? (by + 1) * 128 : K;

  f32x4 acc[4][4];
#pragma unroll
  for (int i = 0; i < 4; i++)
#pragma unroll
    for (int j = 0; j < 4; j++) acc[i][j] = f32x4{0.f, 0.f, 0.f, 0.f};

  const bf16* a_base = As + (wm * 64 + ln) * 32 + rdoff;
  const bf16* b_base = Bs + (wn * 64 + ln) * 32 + rdoff;
  long arow0 = (long)(w * 16 + lr);

  // stage one 128x32 K-slab of A and B into buffer p (4 loads/thread)
#define STG(p, kc0)                                                         \
  {                                                                         \
    int kc = (kc0) + lc;                                                    \
    gload_lds16(A + arow0 * lda + kc, As + (p) * 4096 + w * 512);           \
    gload_lds16(A + (arow0 + 64) * lda + kc,                                \
                As + (p) * 4096 + 2048 + w * 512);                          \
    gload_lds16(Bp + arow0 * ldb + kc, Bs + (p) * 4096 + w * 512);          \
    gload_lds16(Bp + (arow0 + 64) * ldb + kc,                               \
                Bs + (p) * 4096 + 2048 + w * 512);                          \
  }

  STG(0, 0);
  int cur = 0;
  for (int k = 0; k < Keff; k += 32) {
    // own prefetch (issued last iter, latency hidden under last MFMA phase)
    asm volatile("s_waitcnt vmcnt(0)" ::: "memory");
    // raw barrier: (a) everyone's stage for buf cur landed, (b) everyone is
    // done reading buf cur^1 -> safe to overwrite. No implicit drain.
    __builtin_amdgcn_s_barrier();
    __builtin_amdgcn_sched_barrier(0);  // pin ds_reads below the barrier
    if (k + 32 < Keff) STG(cur ^ 1, k + 32);  // prefetch next slab
    bf16x8 af[4], bfr[4];
#pragma unroll
    for (int i = 0; i < 4; i++) {
      af[i] = *(const bf16x8*)(a_base + cur * 4096 + i * 512);
      bfr[i] = *(const bf16x8*)(b_base + cur * 4096 + i * 512);
    }
#pragma unroll
    for (int i = 0; i < 4; i++)
#pragma unroll
      for (int j = 0; j < 4; j++)
        acc[i][j] = __builtin_amdgcn_mfma_f32_16x16x32_bf16(
            af[i], bfr[j], acc[i][j], 0, 0, 0);
    cur ^= 1;
  }
#undef STG
  __syncthreads();  // epilogues below reuse smem as a bounce buffer

  // epilogue: within each 16x16 tile, C row = quad*4 + r, col = ln
  if (MODE == 0) {
    if (vTp && n0 >= 2048) {
      // V-region: bounce through LDS, write transposed to vT[b][d][s].
      int d0 = (int)n0 - 2048;
      int b = (int)(m0 >> 11);
      int s0 = (int)(m0 & 2047);
#pragma unroll
      for (int i = 0; i < 4; i++) {
        int sb = wm * 64 + i * 16 + quad * 4;
#pragma unroll
        for (int j = 0; j < 4; j++) {
          int d = wn * 64 + j * 16 + ln;
          float bv_ = bias[n0 + d];
#pragma unroll
          for (int r = 0; r < 4; r++)
            smem[d * 128 + ((sb + r) ^ (ln << 3))] = (bf16)(acc[i][j][r] + bv_);
        }
      }
      __syncthreads();
      int d = t >> 1, h = t & 1;
      bf16* dst = vTp + (long)b * DD * SS + (long)(d0 + d) * SS + s0 + h * 64;
#pragma unroll
      for (int j = 0; j < 8; j++) {
        int sbase = h * 64 + j * 8;
        bf16x8 v = *(const bf16x8*)(smem + d * 128 + (sbase ^ ((d & 15) << 3)));
        *(bf16x8*)(dst + j * 8) = v;
      }
    } else {
      bf16* C = (bf16*)Cg + (long)bz * sCb + m0 * ldc + n0;
#pragma unroll
      for (int i = 0; i < 4; i++) {
        int rb = wm * 64 + i * 16 + quad * 4;
#pragma unroll
        for (int j = 0; j < 4; j++) {
          int col = wn * 64 + j * 16 + ln;
          float bv_ = bias ? bias[n0 + col] : 0.f;
#pragma unroll
          for (int r = 0; r < 4; r++)
            C[(long)(rb + r) * ldc + col] = (bf16)(acc[i][j][r] + bv_);
        }
      }
    }
  } else if (MODE == 1) {
    // fused-exp epilogue: p~ = exp(scale*acc), 0 above diagonal.
    // store to smem[row*128 + (col ^ ((row&15)<<3))] (chunk-slot swizzle)
#pragma unroll
    for (int i = 0; i < 4; i++) {
      int rb = wm * 64 + i * 16 + quad * 4;
#pragma unroll
      for (int j = 0; j < 4; j++) {
        int col = wn * 64 + j * 16 + ln;
#pragma unroll
        for (int r = 0; r < 4; r++) {
          int row = rb + r;
          float p = 0.f;
          if (n0 + col <= m0 + row) p = __expf(acc[i][j][r] * scale);
          smem[row * 128 + (col ^ ((row & 15) << 3))] = (bf16)p;
        }
      }
    }
    __syncthreads();
    // copy-out: thread t -> row t>>1, 64-col half t&1; sum bf16-rounded p~
    int row = t >> 1, h = t & 1;
    bf16* P = (bf16*)Cg + (long)bz * sCb + (m0 + row) * ldc + n0;
    float rsum = 0.f;
#pragma unroll
    for (int jj = 0; jj < 8; jj++) {
      int p8 = h * 8 + jj;              // 16B chunk index within 128 cols
      int slot = p8 ^ (row & 15);
      bf16x8 v = *(const bf16x8*)(smem + row * 128 + slot * 8);
#pragma unroll
      for (int e = 0; e < 8; e++) rsum += (float)v[e];
      *(bf16x8*)(P + p8 * 8) = v;
    }
    atomicAdd(&rowsums[(long)bz * SS + m0 + row], rsum);
  } else {
    // MODE 2: out = (P~ @ V) / rowsum
    float* C = (float*)Cg + (long)bz * sCb + m0 * ldc + n0;
    const float* rs = rowsums + (long)bz * SS + m0;
#pragma unroll
    for (int i = 0; i < 4; i++) {
      int rb = wm * 64 + i * 16 + quad * 4;
      float inv[4];
#pragma unroll
      for (int r = 0; r < 4; r++) inv[r] = 1.f / rs[rb + r];
#pragma unroll
      for (int j = 0; j < 4; j++) {
        int col = wn * 64 + j * 16 + ln;
#pragma unroll
        for (int r = 0; r < 4; r++)
          C[(long)(rb + r) * ldc + col] = acc[i][j][r] * inv[r];
      }
    }
  }
}

extern "C" void kernel_launch(void* const* d_in, const int* in_sizes, int n_in,
                              void* d_out, int out_size, void* d_ws,
                              size_t ws_size, hipStream_t stream) {
  const float* x = (const float*)d_in[0];
  const float* R = (const float*)d_in[1];
  const float* E = (const float*)d_in[2];
  const float* Wq = (const float*)d_in[3];
  const float* bq = (const float*)d_in[4];
  const float* Wk = (const float*)d_in[5];
  const float* bk = (const float*)d_in[6];
  const float* Wv = (const float*)d_in[7];
  const float* bv = (const float*)d_in[8];
  float* out = (float*)d_out;

  char* ws = (char*)d_ws;
  // Layout (128 MiB total, NO aliasing):
  //   qkv     @ 0       : 8192*3072 bf16 (V cols unused)  = 48 MiB
  //   vT      @ 48 MiB  : 4*1024*2048 bf16                = 16 MiB
  //   probs   @ 64 MiB  : 4*2048*2048 bf16 (unnormalized) = 32 MiB
  //   rowsums @ 96 MiB  : 8192 f32                        = 32 KiB
  //   prep    @ 97 MiB  : xb 16 | Rb 2 | Eb 2 | WqT 2 | WkT 2 | wcat 6 | bias
  bf16* qkv = (bf16*)ws;
  bf16* vT = (bf16*)(ws + 50331648);
  bf16* probs = (bf16*)(ws + 67108864);
  float* rowsums = (float*)(ws + 100663296);
  char* sr = ws + 101711872;
  bf16* xb = (bf16*)sr;                   // 16 MiB
  bf16* Rb = (bf16*)(sr + 16777216);      // 2 MiB
  bf16* Eb = Rb + 1024 * 1024;            // 2 MiB
  bf16* WqT = (bf16*)(sr + 20971520);     // 2 MiB
  bf16* WkT = WqT + 1024 * 1024;          // 2 MiB
  bf16* wcat = (bf16*)(sr + 25165824);    // 6 MiB (Wq'|Wk'|Wv)
  float* bias = (float*)(sr + 31457280);  // 12 KiB

  // 1) all preprocessing + rowsum zeroing: 1 dispatch
  prep_all<<<16416, 256, 0, stream>>>(x, R, E, Wv, Wq, Wk, bq, bk, bv, xb, Rb,
                                      Eb, wcat + 2048 * DD, WqT, WkT, bias,
                                      rowsums);

  // 2) fold weights (batched bz=2): Wq' = R@Wq ; Wk' = E@Wk
  gemm_bt<0><<<dim3(8, 8, 2), 256, 0, stream>>>(
      Rb, DD, 1024 * 1024, WqT, DD, 1024 * 1024, wcat, DD, 1024 * 1024,
      nullptr, 1.f, DD, nullptr, nullptr);

  // 3) fused QKV (M=8192, N=3072, K=1024); V-tiles written transposed to vT
  gemm_bt<0><<<dim3(24, 64, 1), 256, 0, stream>>>(xb, DD, 0, wcat, DD, 0, qkv,
                                                  3072, 0, bias, 1.f, DD, vT,
                                                  nullptr);

  // 4) causal scores + fused exp -> bf16 probs + row sums (136 tri tiles)
  gemm_bt<1><<<dim3(136, 1, BB), 256, 0, stream>>>(
      qkv, 3072, (long)SS * 3072, qkv + 1024, 3072, (long)SS * 3072, probs,
      SS, (long)SS * SS, nullptr, 0.03125f, DD, nullptr, rowsums);

  // 5) out = (P~ @ V) / rowsum : K truncated causally, long strips first
  gemm_bt<2><<<dim3(8, 16, BB), 256, 0, stream>>>(
      probs, SS, (long)SS * SS, vT, SS, (long)DD * SS, out,
      DD, (long)SS * DD, nullptr, 1.f, SS, nullptr, rowsums);
}

// Round 3
// 294.297 us; speedup vs baseline: 1.0303x; 1.0130x over previous
//
#include <hip/hip_runtime.h>
#include <hip/hip_bf16.h>
#include <stdint.h>
#include <math.h>

// Problem constants
#define DD 1024
#define SS 2048
#define BB 4

typedef __bf16 bf16;
typedef __bf16 bf16x8 __attribute__((ext_vector_type(8)));
typedef __bf16 bf16x4 __attribute__((ext_vector_type(4)));
typedef float f32x4 __attribute__((ext_vector_type(4)));

// ---- async global->LDS 16B copy (dest = wave-uniform base + lane*16) ----
__device__ __forceinline__ void gload_lds16(const bf16* g, bf16* l) {
  __builtin_amdgcn_global_load_lds(
      (const __attribute__((address_space(1))) void*)g,
      (__attribute__((address_space(3))) void*)l, 16, 0, 0);
}

// ---- ALL preprocessing in ONE dispatch --------------------------------
__global__ __launch_bounds__(256) void prep_all(
    const float* __restrict__ x, const float* __restrict__ R,
    const float* __restrict__ E, const float* __restrict__ Wv,
    const float* __restrict__ Wq, const float* __restrict__ Wk,
    const float* __restrict__ bq, const float* __restrict__ bk,
    const float* __restrict__ bv, bf16* __restrict__ xb,
    bf16* __restrict__ Rb, bf16* __restrict__ Eb, bf16* __restrict__ Wvb,
    bf16* __restrict__ WqT, bf16* __restrict__ WkT, float* __restrict__ bias,
    float* __restrict__ rowsums) {
  int bid = blockIdx.x;
  int t = threadIdx.x;
  if (bid < 11264) {
    const float* src;
    bf16* dst;
    int base;
    if (bid < 8192) { src = x; dst = xb; base = bid; }
    else if (bid < 9216) { src = R; dst = Rb; base = bid - 8192; }
    else if (bid < 10240) { src = E; dst = Eb; base = bid - 9216; }
    else { src = Wv; dst = Wvb; base = bid - 10240; }
    int i = (base * 256 + t) * 4;
    float4 v = *(const float4*)(src + i);
    bf16x4 o;
    o.x = (bf16)v.x; o.y = (bf16)v.y; o.z = (bf16)v.z; o.w = (bf16)v.w;
    *(bf16x4*)(dst + i) = o;
  } else if (bid < 13312) {
    int r2 = bid - 11264;
    const float* src = (r2 >= 1024) ? Wk : Wq;
    bf16* dst = (r2 >= 1024) ? WkT : WqT;
    int rem = r2 & 1023;
    int bx = rem & 31, by = rem >> 5;
    __shared__ float tile[32][33];
    int tx = t & 31, ty = t >> 5;
    int xcol = bx * 32 + tx;
    int y0 = by * 32;
    for (int r = ty; r < 32; r += 8)
      tile[r][tx] = src[(y0 + r) * DD + xcol];
    __syncthreads();
    int dx = by * 32 + tx;
    int dy0 = bx * 32;
    for (int r = ty; r < 32; r += 8)
      dst[(dy0 + r) * DD + dx] = (bf16)tile[tx][r];
  } else if (bid < 16384) {
    int e = bid - 13312;  // 0..3071
    if (e >= 2048) { if (t == 0) bias[e] = bv[e - 2048]; return; }
    const float* M = (e < 1024) ? R : E;
    const float* bb = (e < 1024) ? bq : bk;
    int row = e & 1023;
    float s = 0.f;
    for (int f = t; f < DD; f += 256) s += M[row * DD + f] * bb[f];
    for (int o = 32; o >= 1; o >>= 1) s += __shfl_xor(s, o, 64);
    __shared__ float red[4];
    if ((t & 63) == 0) red[t >> 6] = s;
    __syncthreads();
    if (t == 0) bias[e] = red[0] + red[1] + red[2] + red[3];
  } else {
    int idx = (bid - 16384) * 256 + t;  // 0..8191
    rowsums[idx] = 0.f;
  }
}

// =====================================================================
// gemm256_qkv: 256x256-tile phase-interleaved GEMM (m201-template, BK=32)
// C = A @ B^T (+bias); A=xb [8192x1024], B=wcat [3072x1024], C=qkv ldc 3072.
// V-region tiles (n0>=2048) written transposed to vT via swizzled LDS bounce.
// 8 waves (2Mx4N), per-wave 128x64 out. LDS 64KB: A/B double-buffered
// 256x32 K-slabs, XOR-swizzled (slot = chunk ^ ((row>>1)&3), 2-way = free).
// Schedule per K-tile t (2 phases, 16 MFMA each):
//   q0: ds_read A-half0 + all B from buf t&1; stage A(t+1) -> buf (t+1)&1
//       (that slot's last reads closed by tile t-1's final barrier)
//       | bar; lgkm0; MFMA; bar
//   q1: ds_read A-half1; stage B(t+2) -> buf t&1 (B of buf t&1 last read at
//       this tile's q0, closed by the q0 barriers)
//       | bar; lgkm0; MFMA; vmcnt(2); bar
// vmcnt(2) leaves exactly B(t+2)'s 2 loads in flight; guarantees A(t+1),
// B(t+1) resident behind the closing barrier (per-wave ledger: oldest-first
// retirement; every wave waits on its OWN loads, barrier makes it global).
// Issue->wait distance: A 2 phases (~2x16 MFMA), B 3-4 phases.
// Tail (tiles 30,31) peeled: no clamped/dummy stages; vmcnt(0) drain at
// tile 30 close so tile 31's slabs are resident; nothing outstanding after.
// =====================================================================
#define STGA(p, h, kt)                                                       \
  gload_lds16(A + (long)((h) * 128 + w * 16 + srow) * DD + (kt) * 32 + scg,  \
              As + (p) * 8192 + (h) * 4096 + w * 512)
#define STGB(p, h, kt)                                                       \
  gload_lds16(B + (long)((h) * 128 + w * 16 + srow) * DD + (kt) * 32 + scg,  \
              Bs + (p) * 8192 + (h) * 4096 + w * 512)

#define PHASE(p, q, WAITN, ...)                                              \
  {                                                                          \
    bf16x8 af[4];                                                            \
    _Pragma("unroll") for (int i_ = 0; i_ < 4; i_++)                         \
        af[i_] = *(const bf16x8*)(a_base + (p) * 8192 + (q) * 2048 +         \
                                  i_ * 512);                                 \
    if ((q) == 0) {                                                          \
      _Pragma("unroll") for (int j_ = 0; j_ < 4; j_++)                       \
          bfr[j_] = *(const bf16x8*)(b_base + (p) * 8192 + j_ * 512);        \
    }                                                                        \
    __VA_ARGS__;                                                             \
    __builtin_amdgcn_s_barrier();                                            \
    asm volatile("s_waitcnt lgkmcnt(0)" ::: "memory");                       \
    __builtin_amdgcn_sched_barrier(0);                                       \
    __builtin_amdgcn_s_setprio(1);                                           \
    _Pragma("unroll") for (int i_ = 0; i_ < 4; i_++)                         \
        _Pragma("unroll") for (int j_ = 0; j_ < 4; j_++) acc[(q)*4 + i_][j_] \
        = __builtin_amdgcn_mfma_f32_16x16x32_bf16(af[i_], bfr[j_],           \
                                                  acc[(q)*4 + i_][j_], 0, 0, \
                                                  0);                        \
    __builtin_amdgcn_s_setprio(0);                                           \
    __builtin_amdgcn_sched_barrier(0);                                       \
    if ((WAITN) == 2) asm volatile("s_waitcnt vmcnt(2)" ::: "memory");       \
    if ((WAITN) == 0) asm volatile("s_waitcnt vmcnt(0)" ::: "memory");       \
    __builtin_amdgcn_s_barrier();                                            \
    __builtin_amdgcn_sched_barrier(0);                                       \
  }

__global__ __launch_bounds__(512, 2) void gemm256_qkv(
    const bf16* __restrict__ Ag, const bf16* __restrict__ Bg,
    bf16* __restrict__ Cg, const float* __restrict__ bias,
    bf16* __restrict__ vTp) {
  __shared__ __align__(16) bf16 smem[32768];  // As[2][256][32] | Bs[2][256][32]
  bf16* As = smem;
  bf16* Bs = smem + 16384;

  // XCD-chunked bijective swizzle: 384 blocks -> 48 contiguous tiles per XCD
  // (4 A-strips = 2 MiB + shared B panels resident in each XCD L2).
  int id = (int)blockIdx.y * 12 + (int)blockIdx.x;
  int wg = (id & 7) * 48 + (id >> 3);
  int bx = wg % 12, by = wg / 12;
  long m0 = (long)by * 256, n0 = (long)bx * 256;
  const bf16* A = Ag + m0 * DD;
  const bf16* B = Bg + n0 * DD;

  int t = threadIdx.x;
  int w = t >> 6, l = t & 63;
  int wm = w >> 2, wn = w & 3;  // 2 x 4 wave grid
  int ln = l & 15, quad = l >> 4;

  // staging: per 128x32 half-slab, lane l -> row w*16 + (l>>2), LDS slot l&3
  // (dest linear: base + lane*16B); global k-chunk pre-swizzled so
  // LDS[row][slot] = global chunk slot ^ ((row>>1)&3)   (rule #21)
  int srow = l >> 2;
  int scg = ((l & 3) ^ ((l >> 3) & 3)) * 8;
  // frag read: row = fragbase + ln, want chunk quad -> slot quad^((ln>>1)&3)
  int rdslot = (quad ^ ((ln >> 1) & 3)) * 8;
  const bf16* a_base = As + (wm * 128 + ln) * 32 + rdslot;
  const bf16* b_base = Bs + (wn * 64 + ln) * 32 + rdslot;

  f32x4 acc[8][4];
#pragma unroll
  for (int i = 0; i < 8; i++)
#pragma unroll
    for (int j = 0; j < 4; j++) acc[i][j] = f32x4{0.f, 0.f, 0.f, 0.f};
  bf16x8 bfr[4];

  // prologue: A(0), B(0), B(1); vmcnt(2) -> A0+B0 landed, B1 in flight
  STGA(0, 0, 0); STGA(0, 1, 0);
  STGB(0, 0, 0); STGB(0, 1, 0);
  STGB(1, 0, 1); STGB(1, 1, 1);
  asm volatile("s_waitcnt vmcnt(2)" ::: "memory");
  __builtin_amdgcn_s_barrier();
  __builtin_amdgcn_sched_barrier(0);

  // K = 1024 -> 32 K-tiles; full-prefetch iterations (all indices < 32)
#pragma unroll 1
  for (int t2 = 0; t2 < 30; t2 += 2) {
    PHASE(0, 0, -1, { STGA(1, 0, t2 + 1); STGA(1, 1, t2 + 1); })
    PHASE(0, 1, 2, { STGB(0, 0, t2 + 2); STGB(0, 1, t2 + 2); })
    PHASE(1, 0, -1, { STGA(0, 0, t2 + 2); STGA(0, 1, t2 + 2); })
    PHASE(1, 1, 2, { STGB(1, 0, t2 + 3); STGB(1, 1, t2 + 3); })
  }
  // tail: tile 30 (buf0) stages A(31) then drains; tile 31 (buf1) pure
  PHASE(0, 0, -1, { STGA(1, 0, 31); STGA(1, 1, 31); })
  PHASE(0, 1, 0, {})
  PHASE(1, 0, -1, {})
  PHASE(1, 1, -1, {})

  // ---- epilogue: row = mf*16 + quad*4 + r (within wave strip), col = ln ---
  if (n0 < 2048) {
    bf16* C = Cg + m0 * 3072 + n0;
#pragma unroll
    for (int mf = 0; mf < 8; mf++) {
      int rb = wm * 128 + mf * 16 + quad * 4;
#pragma unroll
      for (int nf = 0; nf < 4; nf++) {
        int col = wn * 64 + nf * 16 + ln;
        float bv_ = bias[n0 + col];
#pragma unroll
        for (int r = 0; r < 4; r++)
          C[(long)(rb + r) * 3072 + col] = (bf16)(acc[mf][nf][r] + bv_);
      }
    }
  } else {
    // V region: bounce to smem[256 d][128 s] per s-half, write vT[b][d][s]
    int d0 = (int)n0 - 2048;
    int b = (int)(m0 >> 11);
    int s0 = (int)(m0 & 2047);
    for (int h = 0; h < 2; ++h) {
      __syncthreads();  // fences staged-LDS / prior-half reads vs overwrite
      if (wm == h) {
#pragma unroll
        for (int mf = 0; mf < 8; mf++) {
          int sl = mf * 16 + quad * 4;
#pragma unroll
          for (int nf = 0; nf < 4; nf++) {
            int d = wn * 64 + nf * 16 + ln;
            float bv_ = bias[n0 + d];
#pragma unroll
            for (int r = 0; r < 4; r++)
              smem[d * 128 + ((sl + r) ^ ((d & 7) << 3))] =
                  (bf16)(acc[mf][nf][r] + bv_);
          }
        }
      }
      __syncthreads();
      int d = t >> 1, sh = t & 1;
      bf16* dst = vTp + (long)b * DD * SS + (long)(d0 + d) * SS + s0 +
                  h * 128 + sh * 64;
#pragma unroll
      for (int c = 0; c < 8; ++c) {
        int sc = (sh * 64 + c * 8) ^ ((d & 7) << 3);
        *(bf16x8*)(dst + c * 8) = *(const bf16x8*)(smem + d * 128 + sc);
      }
    }
  }
}

// ---- generic bf16 GEMM: 128x128 tiles (fold / scores / PV) -------------
// MODE 0: C bf16 (+bias).
// MODE 1: causal scores with FUSED EXP -> bf16 probs + rowsums.
// MODE 2: P~ @ V with causal K truncation; epilogue divides by rowsums.
template <int MODE>
__global__ __launch_bounds__(256, 4)
void gemm_bt(const bf16* __restrict__ Ag, long lda, long sAb,
             const bf16* __restrict__ Bg, long ldb, long sBb,
             void* __restrict__ Cg, long ldc, long sCb,
             const float* __restrict__ bias, float scale, int K,
             bf16* __restrict__ vTp, float* __restrict__ rowsums) {
  __shared__ __align__(16) bf16 smem[16384];  // As | Bs ; reused for bounce
  bf16* As = smem;
  bf16* Bs = smem + 8192;

  int bx = blockIdx.x, by = blockIdx.y, bz = blockIdx.z;
  if (MODE == 0 || MODE == 1) {
    int nx = (int)gridDim.x;
    int nwg = nx * (int)gridDim.y;
    int id = by * nx + bx;
    int xcd = id & 7, rest = id >> 3;
    int q8 = nwg >> 3, r8 = nwg & 7;
    int wg = (xcd < r8 ? xcd * (q8 + 1) : r8 * (q8 + 1) + (xcd - r8) * q8)
             + rest;
    bx = wg % nx;
    by = wg / nx;
  }
  if (MODE == 1) {  // triangular decode: q -> (by, bx<=by)
    int q = bx;
    by = (int)((sqrtf(8.f * q + 1.f) - 1.f) * 0.5f);
    while ((by + 1) * (by + 2) / 2 <= q) by++;
    while (by * (by + 1) / 2 > q) by--;
    bx = q - by * (by + 1) / 2;
  }
  if (MODE == 2) by = 15 - by;  // longest K strips dispatch first
  long m0 = (long)by * 128, n0 = (long)bx * 128;
  const bf16* A = Ag + (long)bz * sAb + m0 * lda;
  const bf16* Bp = Bg + (long)bz * sBb + n0 * ldb;

  int t = threadIdx.x;
  int w = t >> 6, l = t & 63;
  int lr = l >> 2;
  int lc = (((l & 3) ^ (lr & 3)) * 8);  // swizzled source chunk
  int quad = l >> 4, ln = l & 15;
  int wm = w >> 1, wn = w & 1;
  int rdoff = ((quad ^ (ln & 3)) * 8);  // swizzled read offset

  int Keff = (MODE == 2) ? (by + 1) * 128 : K;

  f32x4 acc[4][4];
#pragma unroll
  for (int i = 0; i < 4; i++)
#pragma unroll
    for (int j = 0; j < 4; j++) acc[i][j] = f32x4{0.f, 0.f, 0.f, 0.f};

  const bf16* a_base = As + (wm * 64 + ln) * 32 + rdoff;
  const bf16* b_base = Bs + (wn * 64 + ln) * 32 + rdoff;
  long arow0 = (long)(w * 16 + lr);

#define STG(p, kc0)                                                         \
  {                                                                         \
    int kc = (kc0) + lc;                                                    \
    gload_lds16(A + arow0 * lda + kc, As + (p) * 4096 + w * 512);           \
    gload_lds16(A + (arow0 + 64) * lda + kc,                                \
                As + (p) * 4096 + 2048 + w * 512);                          \
    gload_lds16(Bp + arow0 * ldb + kc, Bs + (p) * 4096 + w * 512);          \
    gload_lds16(Bp + (arow0 + 64) * ldb + kc,                               \
                Bs + (p) * 4096 + 2048 + w * 512);                          \
  }

  STG(0, 0);
  int cur = 0;
  for (int k = 0; k < Keff; k += 32) {
    asm volatile("s_waitcnt vmcnt(0)" ::: "memory");
    __builtin_amdgcn_s_barrier();
    __builtin_amdgcn_sched_barrier(0);
    if (k + 32 < Keff) STG(cur ^ 1, k + 32);
    bf16x8 af[4], bfr[4];
#pragma unroll
    for (int i = 0; i < 4; i++) {
      af[i] = *(const bf16x8*)(a_base + cur * 4096 + i * 512);
      bfr[i] = *(const bf16x8*)(b_base + cur * 4096 + i * 512);
    }
#pragma unroll
    for (int i = 0; i < 4; i++)
#pragma unroll
      for (int j = 0; j < 4; j++)
        acc[i][j] = __builtin_amdgcn_mfma_f32_16x16x32_bf16(
            af[i], bfr[j], acc[i][j], 0, 0, 0);
    cur ^= 1;
  }
#undef STG
  __syncthreads();  // epilogues below reuse smem as a bounce buffer

  if (MODE == 0) {
    bf16* C = (bf16*)Cg + (long)bz * sCb + m0 * ldc + n0;
#pragma unroll
    for (int i = 0; i < 4; i++) {
      int rb = wm * 64 + i * 16 + quad * 4;
#pragma unroll
      for (int j = 0; j < 4; j++) {
        int col = wn * 64 + j * 16 + ln;
        float bv_ = bias ? bias[n0 + col] : 0.f;
#pragma unroll
        for (int r = 0; r < 4; r++)
          C[(long)(rb + r) * ldc + col] = (bf16)(acc[i][j][r] + bv_);
      }
    }
  } else if (MODE == 1) {
#pragma unroll
    for (int i = 0; i < 4; i++) {
      int rb = wm * 64 + i * 16 + quad * 4;
#pragma unroll
      for (int j = 0; j < 4; j++) {
        int col = wn * 64 + j * 16 + ln;
#pragma unroll
        for (int r = 0; r < 4; r++) {
          int row = rb + r;
          float p = 0.f;
          if (n0 + col <= m0 + row) p = __expf(acc[i][j][r] * scale);
          smem[row * 128 + (col ^ ((row & 15) << 3))] = (bf16)p;
        }
      }
    }
    __syncthreads();
    int row = t >> 1, h = t & 1;
    bf16* P = (bf16*)Cg + (long)bz * sCb + (m0 + row) * ldc + n0;
    float rsum = 0.f;
#pragma unroll
    for (int jj = 0; jj < 8; jj++) {
      int p8 = h * 8 + jj;
      int slot = p8 ^ (row & 15);
      bf16x8 v = *(const bf16x8*)(smem + row * 128 + slot * 8);
#pragma unroll
      for (int e = 0; e < 8; e++) rsum += (float)v[e];
      *(bf16x8*)(P + p8 * 8) = v;
    }
    atomicAdd(&rowsums[(long)bz * SS + m0 + row], rsum);
  } else {
    float* C = (float*)Cg + (long)bz * sCb + m0 * ldc + n0;
    const float* rs = rowsums + (long)bz * SS + m0;
#pragma unroll
    for (int i = 0; i < 4; i++) {
      int rb = wm * 64 + i * 16 + quad * 4;
      float inv[4];
#pragma unroll
      for (int r = 0; r < 4; r++) inv[r] = 1.f / rs[rb + r];
#pragma unroll
      for (int j = 0; j < 4; j++) {
        int col = wn * 64 + j * 16 + ln;
#pragma unroll
        for (int r = 0; r < 4; r++)
          C[(long)(rb + r) * ldc + col] = acc[i][j][r] * inv[r];
      }
    }
  }
}

extern "C" void kernel_launch(void* const* d_in, const int* in_sizes, int n_in,
                              void* d_out, int out_size, void* d_ws,
                              size_t ws_size, hipStream_t stream) {
  const float* x = (const float*)d_in[0];
  const float* R = (const float*)d_in[1];
  const float* E = (const float*)d_in[2];
  const float* Wq = (const float*)d_in[3];
  const float* bq = (const float*)d_in[4];
  const float* Wk = (const float*)d_in[5];
  const float* bk = (const float*)d_in[6];
  const float* Wv = (const float*)d_in[7];
  const float* bv = (const float*)d_in[8];
  float* out = (float*)d_out;

  char* ws = (char*)d_ws;
  bf16* qkv = (bf16*)ws;
  bf16* vT = (bf16*)(ws + 50331648);
  bf16* probs = (bf16*)(ws + 67108864);
  float* rowsums = (float*)(ws + 100663296);
  char* sr = ws + 101711872;
  bf16* xb = (bf16*)sr;                   // 16 MiB
  bf16* Rb = (bf16*)(sr + 16777216);      // 2 MiB
  bf16* Eb = Rb + 1024 * 1024;            // 2 MiB
  bf16* WqT = (bf16*)(sr + 20971520);     // 2 MiB
  bf16* WkT = WqT + 1024 * 1024;          // 2 MiB
  bf16* wcat = (bf16*)(sr + 25165824);    // 6 MiB (Wq'|Wk'|Wv)
  float* bias = (float*)(sr + 31457280);  // 12 KiB

  // 1) all preprocessing + rowsum zeroing: 1 dispatch
  prep_all<<<16416, 256, 0, stream>>>(x, R, E, Wv, Wq, Wk, bq, bk, bv, xb, Rb,
                                      Eb, wcat + 2048 * DD, WqT, WkT, bias,
                                      rowsums);

  // 2) fold weights (batched bz=2): Wq' = R@Wq ; Wk' = E@Wk
  gemm_bt<0><<<dim3(8, 8, 2), 256, 0, stream>>>(
      Rb, DD, 1024 * 1024, WqT, DD, 1024 * 1024, wcat, DD, 1024 * 1024,
      nullptr, 1.f, DD, nullptr, nullptr);

  // 3) fused QKV (M=8192, N=3072, K=1024) on the 256-tile phase template;
  //    V-tiles written transposed to vT
  gemm256_qkv<<<dim3(12, 32, 1), 512, 0, stream>>>(xb, wcat, qkv, bias, vT);

  // 4) causal scores + fused exp -> bf16 probs + row sums (136 tri tiles)
  gemm_bt<1><<<dim3(136, 1, BB), 256, 0, stream>>>(
      qkv, 3072, (long)SS * 3072, qkv + 1024, 3072, (long)SS * 3072, probs,
      SS, (long)SS * SS, nullptr, 0.03125f, DD, nullptr, rowsums);

  // 5) out = (P~ @ V) / rowsum : K truncated causally, long strips first
  gemm_bt<2><<<dim3(8, 16, BB), 256, 0, stream>>>(
      probs, SS, (long)SS * SS, vT, SS, (long)DD * SS, out,
      DD, (long)SS * DD, nullptr, 1.f, SS, nullptr, rowsums);
}

// Round 4
// 293.221 us; speedup vs baseline: 1.0341x; 1.0037x over previous
//
#include <hip/hip_runtime.h>
#include <hip/hip_bf16.h>
#include <stdint.h>
#include <math.h>

// Problem constants
#define DD 1024
#define SS 2048
#define BB 4

typedef __bf16 bf16;
typedef __bf16 bf16x8 __attribute__((ext_vector_type(8)));
typedef __bf16 bf16x4 __attribute__((ext_vector_type(4)));
typedef float f32x4 __attribute__((ext_vector_type(4)));

// ---- async global->LDS 16B copy (dest = wave-uniform base + lane*16) ----
__device__ __forceinline__ void gload_lds16(const bf16* g, bf16* l) {
  __builtin_amdgcn_global_load_lds(
      (const __attribute__((address_space(1))) void*)g,
      (__attribute__((address_space(3))) void*)l, 16, 0, 0);
}

// ---- ALL preprocessing in ONE dispatch --------------------------------
__global__ __launch_bounds__(256) void prep_all(
    const float* __restrict__ x, const float* __restrict__ R,
    const float* __restrict__ E, const float* __restrict__ Wv,
    const float* __restrict__ Wq, const float* __restrict__ Wk,
    const float* __restrict__ bq, const float* __restrict__ bk,
    const float* __restrict__ bv, bf16* __restrict__ xb,
    bf16* __restrict__ Rb, bf16* __restrict__ Eb, bf16* __restrict__ Wvb,
    bf16* __restrict__ WqT, bf16* __restrict__ WkT, float* __restrict__ bias,
    float* __restrict__ rowsums) {
  int bid = blockIdx.x;
  int t = threadIdx.x;
  if (bid < 11264) {
    const float* src;
    bf16* dst;
    int base;
    if (bid < 8192) { src = x; dst = xb; base = bid; }
    else if (bid < 9216) { src = R; dst = Rb; base = bid - 8192; }
    else if (bid < 10240) { src = E; dst = Eb; base = bid - 9216; }
    else { src = Wv; dst = Wvb; base = bid - 10240; }
    int i = (base * 256 + t) * 4;
    float4 v = *(const float4*)(src + i);
    bf16x4 o;
    o.x = (bf16)v.x; o.y = (bf16)v.y; o.z = (bf16)v.z; o.w = (bf16)v.w;
    *(bf16x4*)(dst + i) = o;
  } else if (bid < 13312) {
    int r2 = bid - 11264;
    const float* src = (r2 >= 1024) ? Wk : Wq;
    bf16* dst = (r2 >= 1024) ? WkT : WqT;
    int rem = r2 & 1023;
    int bx = rem & 31, by = rem >> 5;
    __shared__ float tile[32][33];
    int tx = t & 31, ty = t >> 5;
    int xcol = bx * 32 + tx;
    int y0 = by * 32;
    for (int r = ty; r < 32; r += 8)
      tile[r][tx] = src[(y0 + r) * DD + xcol];
    __syncthreads();
    int dx = by * 32 + tx;
    int dy0 = bx * 32;
    for (int r = ty; r < 32; r += 8)
      dst[(dy0 + r) * DD + dx] = (bf16)tile[tx][r];
  } else if (bid < 16384) {
    int e = bid - 13312;  // 0..3071
    if (e >= 2048) { if (t == 0) bias[e] = bv[e - 2048]; return; }
    const float* M = (e < 1024) ? R : E;
    const float* bb = (e < 1024) ? bq : bk;
    int row = e & 1023;
    float s = 0.f;
    for (int f = t; f < DD; f += 256) s += M[row * DD + f] * bb[f];
    for (int o = 32; o >= 1; o >>= 1) s += __shfl_xor(s, o, 64);
    __shared__ float red[4];
    if ((t & 63) == 0) red[t >> 6] = s;
    __syncthreads();
    if (t == 0) bias[e] = red[0] + red[1] + red[2] + red[3];
  } else {
    int idx = (bid - 16384) * 256 + t;  // 0..8191
    rowsums[idx] = 0.f;
  }
}

// =====================================================================
// gemm_qkv: 128x256-tile GEMM, one 16-MFMA phase per K-tile (BK=32).
// C = A @ B^T (+bias); A=xb [8192x1024], B=wcat [3072x1024], C=qkv ldc 3072.
// V-region tiles (bx>=8) written transposed to vT via swizzled LDS bounce.
// 8 waves (2Mx4N), per-wave 64x64 (acc[4][4]). Grid 12x64 = 768 blocks
// (2 resident/CU + 256-block backfill pool -> good load balance).
// LDS exactly 64KB static: A double-buffered (2 x 128x32 = 16KB, prefetch
// distance 1, covered by the 16-MFMA block) + B TRIPLE-buffered
// (3 x 256x32 = 48KB, prefetch distance 2 ~ covers L3/HBM latency).
// Per tile t: {ds_read bufA[t&1], bufB[t%3]; stage A(t+1)->A^1 (1 ld/thr),
//   B(t+2)->B[(t+2)%3] (2 ld/thr); bar; lgkm0; 16 MFMA; vmcnt(2); bar}
// vmcnt ledger at wait: queue = [B(t+1):2, A(t+1):1, B(t+2):2] -> vmcnt(2)
// drains B(t+1)+A(t+1) (needed next tile), leaves B(t+2) in flight. Never
// 0 in the loop. Race-free: every staged slot's last reader finished before
// the PREVIOUS closing barrier (reads complete at own lgkm0 before MFMA).
// Tail peeled: tile 30 stages A(31) then vmcnt(0); tile 31 pure.
// =====================================================================
#define QSTGA(pa, kt)                                                        \
  gload_lds16(A + (long)(w * 16 + srow) * DD + (kt) * 32 + scg,              \
              As + (pa) * 4096 + w * 512)
#define QSTGB(pb, h, kt)                                                     \
  gload_lds16(B + (long)((h) * 128 + w * 16 + srow) * DD + (kt) * 32 + scg,  \
              Bs + (pb) * 8192 + (h) * 4096 + w * 512)

#define QTILE(pa, pb, pa1, pb2, kA, kB, DOA, DOB, WAITN)                     \
  {                                                                          \
    bf16x8 af[4], bfr[4];                                                    \
    _Pragma("unroll") for (int i_ = 0; i_ < 4; i_++)                         \
        af[i_] = *(const bf16x8*)(a_base + (pa) * 4096 + i_ * 512);          \
    _Pragma("unroll") for (int j_ = 0; j_ < 4; j_++)                         \
        bfr[j_] = *(const bf16x8*)(b_base + (pb) * 8192 + j_ * 512);         \
    if (DOA) { QSTGA(pa1, kA); }                                             \
    if (DOB) { QSTGB(pb2, 0, kB); QSTGB(pb2, 1, kB); }                       \
    __builtin_amdgcn_s_barrier();                                            \
    asm volatile("s_waitcnt lgkmcnt(0)" ::: "memory");                       \
    __builtin_amdgcn_sched_barrier(0);                                       \
    __builtin_amdgcn_s_setprio(1);                                           \
    _Pragma("unroll") for (int i_ = 0; i_ < 4; i_++)                         \
        _Pragma("unroll") for (int j_ = 0; j_ < 4; j_++) acc[i_][j_] =       \
        __builtin_amdgcn_mfma_f32_16x16x32_bf16(af[i_], bfr[j_],             \
                                                acc[i_][j_], 0, 0, 0);       \
    __builtin_amdgcn_s_setprio(0);                                           \
    __builtin_amdgcn_sched_barrier(0);                                       \
    if ((WAITN) == 2) asm volatile("s_waitcnt vmcnt(2)" ::: "memory");       \
    if ((WAITN) == 0) asm volatile("s_waitcnt vmcnt(0)" ::: "memory");       \
    __builtin_amdgcn_s_barrier();                                            \
    __builtin_amdgcn_sched_barrier(0);                                       \
  }

__global__ __launch_bounds__(512, 4) void gemm_qkv(
    const bf16* __restrict__ Ag, const bf16* __restrict__ Bg,
    bf16* __restrict__ Cg, const float* __restrict__ bias,
    bf16* __restrict__ vTp) {
  // As[2][128][32] (8192) | Bs[3][256][32] (24576)  = 32768 bf16 = 64 KB
  __shared__ __align__(16) bf16 smem[32768];
  bf16* As = smem;
  bf16* Bs = smem + 8192;

  // XCD-chunked bijective swizzle, 96 tiles/XCD as 3bx x 32by so the
  // B-panel slice (3 x 256 x 1024 x 2B = 1.5 MiB) stays L2-resident.
  int id = (int)blockIdx.y * 12 + (int)blockIdx.x;
  int wg = (id & 7) * 96 + (id >> 3);
  int ck = wg / 96, r96 = wg % 96;
  int bx = (ck & 3) * 3 + r96 % 3;
  int by = (ck >> 2) * 32 + r96 / 3;
  long m0 = (long)by * 128, n0 = (long)bx * 256;
  const bf16* A = Ag + m0 * DD;
  const bf16* B = Bg + n0 * DD;

  int t = threadIdx.x;
  int w = t >> 6, l = t & 63;
  int wm = w >> 2, wn = w & 3;  // 2 x 4 wave grid; per-wave 64x64
  int ln = l & 15, quad = l >> 4;

  // staging: lane l -> row w*16 + (l>>2), slot l&3; source k-chunk
  // pre-swizzled so LDS[row][slot] = global chunk slot^((row>>1)&3)
  int srow = l >> 2;
  int scg = ((l & 3) ^ ((l >> 3) & 3)) * 8;
  // frag read: row = fragbase + ln; chunk quad -> slot quad^((ln>>1)&3)
  int rdslot = (quad ^ ((ln >> 1) & 3)) * 8;
  const bf16* a_base = As + (wm * 64 + ln) * 32 + rdslot;
  const bf16* b_base = Bs + (wn * 64 + ln) * 32 + rdslot;

  f32x4 acc[4][4];
#pragma unroll
  for (int i = 0; i < 4; i++)
#pragma unroll
    for (int j = 0; j < 4; j++) acc[i][j] = f32x4{0.f, 0.f, 0.f, 0.f};

  // prologue: A(0), B(0), B(1); vmcnt(2) -> A0+B0 landed, B1 in flight
  QSTGA(0, 0);
  QSTGB(0, 0, 0); QSTGB(0, 1, 0);
  QSTGB(1, 0, 1); QSTGB(1, 1, 1);
  asm volatile("s_waitcnt vmcnt(2)" ::: "memory");
  __builtin_amdgcn_s_barrier();
  __builtin_amdgcn_sched_barrier(0);

  // K=1024 -> 32 K-tiles; buffers cycle lcm(2,3)=6 -> unroll 6.
  // Tiles 0..29 in the loop (stage indices <= 31), tiles 30,31 peeled.
#pragma unroll 1
  for (int t6 = 0; t6 < 30; t6 += 6) {
    QTILE(0, 0, 1, 2, t6 + 1, t6 + 2, 1, 1, 2)
    QTILE(1, 1, 0, 0, t6 + 2, t6 + 3, 1, 1, 2)
    QTILE(0, 2, 1, 1, t6 + 3, t6 + 4, 1, 1, 2)
    QTILE(1, 0, 0, 2, t6 + 4, t6 + 5, 1, 1, 2)
    QTILE(0, 1, 1, 0, t6 + 5, t6 + 6, 1, 1, 2)
    QTILE(1, 2, 0, 1, t6 + 6, t6 + 7, 1, 1, 2)
  }
  QTILE(0, 0, 1, 0, 31, 0, 1, 0, 0)   // tile 30: stage A(31), drain all
  QTILE(1, 1, 0, 0, 0, 0, 0, 0, -1)   // tile 31: pure compute

  __syncthreads();  // epilogue below may reuse smem as a bounce buffer

  // ---- epilogue: row = wm*64 + i*16 + quad*4 + r, col = wn*64 + j*16 + ln
  if (n0 < 2048) {
    bf16* C = Cg + m0 * 3072 + n0;
#pragma unroll
    for (int i = 0; i < 4; i++) {
      int rb = wm * 64 + i * 16 + quad * 4;
#pragma unroll
      for (int j = 0; j < 4; j++) {
        int col = wn * 64 + j * 16 + ln;
        float bv_ = bias[n0 + col];
#pragma unroll
        for (int r = 0; r < 4; r++)
          C[(long)(rb + r) * 3072 + col] = (bf16)(acc[i][j][r] + bv_);
      }
    }
  } else {
    // V region: bounce to smem[256 d][128 s], write vT[b][d][s]
    int d0 = (int)n0 - 2048;
    int b = (int)(m0 >> 11);
    int s0 = (int)(m0 & 2047);
#pragma unroll
    for (int i = 0; i < 4; i++) {
      int sl = wm * 64 + i * 16 + quad * 4;
#pragma unroll
      for (int j = 0; j < 4; j++) {
        int d = wn * 64 + j * 16 + ln;
        float bv_ = bias[n0 + d];
#pragma unroll
        for (int r = 0; r < 4; r++)
          smem[d * 128 + ((sl + r) ^ ((d & 7) << 3))] =
              (bf16)(acc[i][j][r] + bv_);
      }
    }
    __syncthreads();
    int d = t >> 1, sh = t & 1;
    bf16* dst = vTp + (long)b * DD * SS + (long)(d0 + d) * SS + s0 + sh * 64;
#pragma unroll
    for (int c = 0; c < 8; ++c) {
      int sc = (sh * 64 + c * 8) ^ ((d & 7) << 3);
      *(bf16x8*)(dst + c * 8) = *(const bf16x8*)(smem + d * 128 + sc);
    }
  }
}

// ---- generic bf16 GEMM: 128x128 tiles (fold / scores / PV) -------------
// MODE 0: C bf16 (+bias).
// MODE 1: causal scores with FUSED EXP -> bf16 probs + rowsums.
// MODE 2: P~ @ V with causal K truncation; epilogue divides by rowsums.
template <int MODE>
__global__ __launch_bounds__(256, 4)
void gemm_bt(const bf16* __restrict__ Ag, long lda, long sAb,
             const bf16* __restrict__ Bg, long ldb, long sBb,
             void* __restrict__ Cg, long ldc, long sCb,
             const float* __restrict__ bias, float scale, int K,
             bf16* __restrict__ vTp, float* __restrict__ rowsums) {
  __shared__ __align__(16) bf16 smem[16384];  // As | Bs ; reused for bounce
  bf16* As = smem;
  bf16* Bs = smem + 8192;

  int bx = blockIdx.x, by = blockIdx.y, bz = blockIdx.z;
  if (MODE == 0 || MODE == 1) {
    int nx = (int)gridDim.x;
    int nwg = nx * (int)gridDim.y;
    int id = by * nx + bx;
    int xcd = id & 7, rest = id >> 3;
    int q8 = nwg >> 3, r8 = nwg & 7;
    int wg = (xcd < r8 ? xcd * (q8 + 1) : r8 * (q8 + 1) + (xcd - r8) * q8)
             + rest;
    bx = wg % nx;
    by = wg / nx;
  }
  if (MODE == 1) {  // triangular decode: q -> (by, bx<=by)
    int q = bx;
    by = (int)((sqrtf(8.f * q + 1.f) - 1.f) * 0.5f);
    while ((by + 1) * (by + 2) / 2 <= q) by++;
    while (by * (by + 1) / 2 > q) by--;
    bx = q - by * (by + 1) / 2;
  }
  if (MODE == 2) by = 15 - by;  // longest K strips dispatch first
  long m0 = (long)by * 128, n0 = (long)bx * 128;
  const bf16* A = Ag + (long)bz * sAb + m0 * lda;
  const bf16* Bp = Bg + (long)bz * sBb + n0 * ldb;

  int t = threadIdx.x;
  int w = t >> 6, l = t & 63;
  int lr = l >> 2;
  int lc = (((l & 3) ^ (lr & 3)) * 8);  // swizzled source chunk
  int quad = l >> 4, ln = l & 15;
  int wm = w >> 1, wn = w & 1;
  int rdoff = ((quad ^ (ln & 3)) * 8);  // swizzled read offset

  int Keff = (MODE == 2) ? (by + 1) * 128 : K;

  f32x4 acc[4][4];
#pragma unroll
  for (int i = 0; i < 4; i++)
#pragma unroll
    for (int j = 0; j < 4; j++) acc[i][j] = f32x4{0.f, 0.f, 0.f, 0.f};

  const bf16* a_base = As + (wm * 64 + ln) * 32 + rdoff;
  const bf16* b_base = Bs + (wn * 64 + ln) * 32 + rdoff;
  long arow0 = (long)(w * 16 + lr);

#define STG(p, kc0)                                                         \
  {                                                                         \
    int kc = (kc0) + lc;                                                    \
    gload_lds16(A + arow0 * lda + kc, As + (p) * 4096 + w * 512);           \
    gload_lds16(A + (arow0 + 64) * lda + kc,                                \
                As + (p) * 4096 + 2048 + w * 512);                          \
    gload_lds16(Bp + arow0 * ldb + kc, Bs + (p) * 4096 + w * 512);          \
    gload_lds16(Bp + (arow0 + 64) * ldb + kc,                               \
                Bs + (p) * 4096 + 2048 + w * 512);                          \
  }

  STG(0, 0);
  int cur = 0;
  for (int k = 0; k < Keff; k += 32) {
    asm volatile("s_waitcnt vmcnt(0)" ::: "memory");
    __builtin_amdgcn_s_barrier();
    __builtin_amdgcn_sched_barrier(0);
    if (k + 32 < Keff) STG(cur ^ 1, k + 32);
    bf16x8 af[4], bfr[4];
#pragma unroll
    for (int i = 0; i < 4; i++) {
      af[i] = *(const bf16x8*)(a_base + cur * 4096 + i * 512);
      bfr[i] = *(const bf16x8*)(b_base + cur * 4096 + i * 512);
    }
#pragma unroll
    for (int i = 0; i < 4; i++)
#pragma unroll
      for (int j = 0; j < 4; j++)
        acc[i][j] = __builtin_amdgcn_mfma_f32_16x16x32_bf16(
            af[i], bfr[j], acc[i][j], 0, 0, 0);
    cur ^= 1;
  }
#undef STG
  __syncthreads();  // epilogues below reuse smem as a bounce buffer

  if (MODE == 0) {
    bf16* C = (bf16*)Cg + (long)bz * sCb + m0 * ldc + n0;
#pragma unroll
    for (int i = 0; i < 4; i++) {
      int rb = wm * 64 + i * 16 + quad * 4;
#pragma unroll
      for (int j = 0; j < 4; j++) {
        int col = wn * 64 + j * 16 + ln;
        float bv_ = bias ? bias[n0 + col] : 0.f;
#pragma unroll
        for (int r = 0; r < 4; r++)
          C[(long)(rb + r) * ldc + col] = (bf16)(acc[i][j][r] + bv_);
      }
    }
  } else if (MODE == 1) {
#pragma unroll
    for (int i = 0; i < 4; i++) {
      int rb = wm * 64 + i * 16 + quad * 4;
#pragma unroll
      for (int j = 0; j < 4; j++) {
        int col = wn * 64 + j * 16 + ln;
#pragma unroll
        for (int r = 0; r < 4; r++) {
          int row = rb + r;
          float p = 0.f;
          if (n0 + col <= m0 + row) p = __expf(acc[i][j][r] * scale);
          smem[row * 128 + (col ^ ((row & 15) << 3))] = (bf16)p;
        }
      }
    }
    __syncthreads();
    int row = t >> 1, h = t & 1;
    bf16* P = (bf16*)Cg + (long)bz * sCb + (m0 + row) * ldc + n0;
    float rsum = 0.f;
#pragma unroll
    for (int jj = 0; jj < 8; jj++) {
      int p8 = h * 8 + jj;
      int slot = p8 ^ (row & 15);
      bf16x8 v = *(const bf16x8*)(smem + row * 128 + slot * 8);
#pragma unroll
      for (int e = 0; e < 8; e++) rsum += (float)v[e];
      *(bf16x8*)(P + p8 * 8) = v;
    }
    atomicAdd(&rowsums[(long)bz * SS + m0 + row], rsum);
  } else {
    float* C = (float*)Cg + (long)bz * sCb + m0 * ldc + n0;
    const float* rs = rowsums + (long)bz * SS + m0;
#pragma unroll
    for (int i = 0; i < 4; i++) {
      int rb = wm * 64 + i * 16 + quad * 4;
      float inv[4];
#pragma unroll
      for (int r = 0; r < 4; r++) inv[r] = 1.f / rs[rb + r];
#pragma unroll
      for (int j = 0; j < 4; j++) {
        int col = wn * 64 + j * 16 + ln;
#pragma unroll
        for (int r = 0; r < 4; r++)
          C[(long)(rb + r) * ldc + col] = acc[i][j][r] * inv[r];
      }
    }
  }
}

extern "C" void kernel_launch(void* const* d_in, const int* in_sizes, int n_in,
                              void* d_out, int out_size, void* d_ws,
                              size_t ws_size, hipStream_t stream) {
  const float* x = (const float*)d_in[0];
  const float* R = (const float*)d_in[1];
  const float* E = (const float*)d_in[2];
  const float* Wq = (const float*)d_in[3];
  const float* bq = (const float*)d_in[4];
  const float* Wk = (const float*)d_in[5];
  const float* bk = (const float*)d_in[6];
  const float* Wv = (const float*)d_in[7];
  const float* bv = (const float*)d_in[8];
  float* out = (float*)d_out;

  char* ws = (char*)d_ws;
  bf16* qkv = (bf16*)ws;
  bf16* vT = (bf16*)(ws + 50331648);
  bf16* probs = (bf16*)(ws + 67108864);
  float* rowsums = (float*)(ws + 100663296);
  char* sr = ws + 101711872;
  bf16* xb = (bf16*)sr;                   // 16 MiB
  bf16* Rb = (bf16*)(sr + 16777216);      // 2 MiB
  bf16* Eb = Rb + 1024 * 1024;            // 2 MiB
  bf16* WqT = (bf16*)(sr + 20971520);     // 2 MiB
  bf16* WkT = WqT + 1024 * 1024;          // 2 MiB
  bf16* wcat = (bf16*)(sr + 25165824);    // 6 MiB (Wq'|Wk'|Wv)
  float* bias = (float*)(sr + 31457280);  // 12 KiB

  // 1) all preprocessing + rowsum zeroing: 1 dispatch
  prep_all<<<16416, 256, 0, stream>>>(x, R, E, Wv, Wq, Wk, bq, bk, bv, xb, Rb,
                                      Eb, wcat + 2048 * DD, WqT, WkT, bias,
                                      rowsums);

  // 2) fold weights (batched bz=2): Wq' = R@Wq ; Wk' = E@Wk
  gemm_bt<0><<<dim3(8, 8, 2), 256, 0, stream>>>(
      Rb, DD, 1024 * 1024, WqT, DD, 1024 * 1024, wcat, DD, 1024 * 1024,
      nullptr, 1.f, DD, nullptr, nullptr);

  // 3) fused QKV (M=8192, N=3072, K=1024), 128x256 tiles, 768 blocks;
  //    V-tiles written transposed to vT
  gemm_qkv<<<dim3(12, 64, 1), 512, 0, stream>>>(xb, wcat, qkv, bias, vT);

  // 4) causal scores + fused exp -> bf16 probs + row sums (136 tri tiles)
  gemm_bt<1><<<dim3(136, 1, BB), 256, 0, stream>>>(
      qkv, 3072, (long)SS * 3072, qkv + 1024, 3072, (long)SS * 3072, probs,
      SS, (long)SS * SS, nullptr, 0.03125f, DD, nullptr, rowsums);

  // 5) out = (P~ @ V) / rowsum : K truncated causally, long strips first
  gemm_bt<2><<<dim3(8, 16, BB), 256, 0, stream>>>(
      probs, SS, (long)SS * SS, vT, SS, (long)DD * SS, out,
      DD, (long)SS * DD, nullptr, 1.f, SS, nullptr, rowsums);
}

// Round 5
// 290.551 us; speedup vs baseline: 1.0436x; 1.0092x over previous
//
#include <hip/hip_runtime.h>
#include <hip/hip_bf16.h>
#include <stdint.h>
#include <math.h>

// Problem constants
#define DD 1024
#define SS 2048
#define BB 4

typedef __bf16 bf16;
typedef __bf16 bf16x8 __attribute__((ext_vector_type(8)));
typedef __bf16 bf16x4 __attribute__((ext_vector_type(4)));
typedef float f32x4 __attribute__((ext_vector_type(4)));

// ---- async global->LDS 16B copy (dest = wave-uniform base + lane*16) ----
__device__ __forceinline__ void gload_lds16(const bf16* g, bf16* l) {
  __builtin_amdgcn_global_load_lds(
      (const __attribute__((address_space(1))) void*)g,
      (__attribute__((address_space(3))) void*)l, 16, 0, 0);
}

// ---- ALL preprocessing in ONE dispatch --------------------------------
__global__ __launch_bounds__(256) void prep_all(
    const float* __restrict__ x, const float* __restrict__ R,
    const float* __restrict__ E, const float* __restrict__ Wv,
    const float* __restrict__ Wq, const float* __restrict__ Wk,
    const float* __restrict__ bq, const float* __restrict__ bk,
    const float* __restrict__ bv, bf16* __restrict__ xb,
    bf16* __restrict__ Rb, bf16* __restrict__ Eb, bf16* __restrict__ Wvb,
    bf16* __restrict__ WqT, bf16* __restrict__ WkT, float* __restrict__ bias,
    float* __restrict__ rowsums) {
  int bid = blockIdx.x;
  int t = threadIdx.x;
  if (bid < 11264) {
    const float* src;
    bf16* dst;
    int base;
    if (bid < 8192) { src = x; dst = xb; base = bid; }
    else if (bid < 9216) { src = R; dst = Rb; base = bid - 8192; }
    else if (bid < 10240) { src = E; dst = Eb; base = bid - 9216; }
    else { src = Wv; dst = Wvb; base = bid - 10240; }
    int i = (base * 256 + t) * 4;
    float4 v = *(const float4*)(src + i);
    bf16x4 o;
    o.x = (bf16)v.x; o.y = (bf16)v.y; o.z = (bf16)v.z; o.w = (bf16)v.w;
    *(bf16x4*)(dst + i) = o;
  } else if (bid < 13312) {
    int r2 = bid - 11264;
    const float* src = (r2 >= 1024) ? Wk : Wq;
    bf16* dst = (r2 >= 1024) ? WkT : WqT;
    int rem = r2 & 1023;
    int bx = rem & 31, by = rem >> 5;
    __shared__ float tile[32][33];
    int tx = t & 31, ty = t >> 5;
    int xcol = bx * 32 + tx;
    int y0 = by * 32;
    for (int r = ty; r < 32; r += 8)
      tile[r][tx] = src[(y0 + r) * DD + xcol];
    __syncthreads();
    int dx = by * 32 + tx;
    int dy0 = bx * 32;
    for (int r = ty; r < 32; r += 8)
      dst[(dy0 + r) * DD + dx] = (bf16)tile[tx][r];
  } else if (bid < 16384) {
    int e = bid - 13312;  // 0..3071
    if (e >= 2048) { if (t == 0) bias[e] = bv[e - 2048]; return; }
    const float* M = (e < 1024) ? R : E;
    const float* bb = (e < 1024) ? bq : bk;
    int row = e & 1023;
    float s = 0.f;
    for (int f = t; f < DD; f += 256) s += M[row * DD + f] * bb[f];
    for (int o = 32; o >= 1; o >>= 1) s += __shfl_xor(s, o, 64);
    __shared__ float red[4];
    if ((t & 63) == 0) red[t >> 6] = s;
    __syncthreads();
    if (t == 0) bias[e] = red[0] + red[1] + red[2] + red[3];
  } else {
    int idx = (bid - 16384) * 256 + t;  // 0..8191
    rowsums[idx] = 0.f;
  }
}

// =====================================================================
// 128x256-tile QTILE structure (shared by gemm_qkv and scores256):
// one 16-MFMA phase per K-tile (BK=32), A double-buffered (dist 1),
// B TRIPLE-buffered (dist 2), counted vmcnt(2) in the loop (never 0),
// LDS exactly 64KB: As[2][128][32] + Bs[3][256][32].
// vmcnt ledger at wait: [B(t+1):2, A(t+1):1, B(t+2):2] -> vmcnt(2) drains
// B(t+1)+A(t+1), leaves B(t+2) in flight. Tail (tiles 30,31) peeled.
// =====================================================================
#define QSTGA(pa, kt)                                                        \
  gload_lds16(A + (long)(w * 16 + srow) * DD + (kt) * 32 + scg,              \
              As + (pa) * 4096 + w * 512)
#define QSTGB(pb, h, kt)                                                     \
  gload_lds16(B + (long)((h) * 128 + w * 16 + srow) * DD + (kt) * 32 + scg,  \
              Bs + (pb) * 8192 + (h) * 4096 + w * 512)

#define QTILE(pa, pb, pa1, pb2, kA, kB, DOA, DOB, WAITN)                     \
  {                                                                          \
    bf16x8 af[4], bfr[4];                                                    \
    _Pragma("unroll") for (int i_ = 0; i_ < 4; i_++)                         \
        af[i_] = *(const bf16x8*)(a_base + (pa) * 4096 + i_ * 512);          \
    _Pragma("unroll") for (int j_ = 0; j_ < 4; j_++)                         \
        bfr[j_] = *(const bf16x8*)(b_base + (pb) * 8192 + j_ * 512);         \
    if (DOA) { QSTGA(pa1, kA); }                                             \
    if (DOB) { QSTGB(pb2, 0, kB); QSTGB(pb2, 1, kB); }                       \
    __builtin_amdgcn_s_barrier();                                            \
    asm volatile("s_waitcnt lgkmcnt(0)" ::: "memory");                       \
    __builtin_amdgcn_sched_barrier(0);                                       \
    __builtin_amdgcn_s_setprio(1);                                           \
    _Pragma("unroll") for (int i_ = 0; i_ < 4; i_++)                         \
        _Pragma("unroll") for (int j_ = 0; j_ < 4; j_++) acc[i_][j_] =       \
        __builtin_amdgcn_mfma_f32_16x16x32_bf16(af[i_], bfr[j_],             \
                                                acc[i_][j_], 0, 0, 0);       \
    __builtin_amdgcn_s_setprio(0);                                           \
    __builtin_amdgcn_sched_barrier(0);                                       \
    if ((WAITN) == 2) asm volatile("s_waitcnt vmcnt(2)" ::: "memory");       \
    if ((WAITN) == 0) asm volatile("s_waitcnt vmcnt(0)" ::: "memory");       \
    __builtin_amdgcn_s_barrier();                                            \
    __builtin_amdgcn_sched_barrier(0);                                       \
  }

#define QPROLOGUE_AND_LOOP                                                   \
  QSTGA(0, 0);                                                               \
  QSTGB(0, 0, 0); QSTGB(0, 1, 0);                                            \
  QSTGB(1, 0, 1); QSTGB(1, 1, 1);                                            \
  asm volatile("s_waitcnt vmcnt(2)" ::: "memory");                           \
  __builtin_amdgcn_s_barrier();                                              \
  __builtin_amdgcn_sched_barrier(0);                                         \
  _Pragma("unroll 1") for (int t6 = 0; t6 < 30; t6 += 6) {                   \
    QTILE(0, 0, 1, 2, t6 + 1, t6 + 2, 1, 1, 2)                               \
    QTILE(1, 1, 0, 0, t6 + 2, t6 + 3, 1, 1, 2)                               \
    QTILE(0, 2, 1, 1, t6 + 3, t6 + 4, 1, 1, 2)                               \
    QTILE(1, 0, 0, 2, t6 + 4, t6 + 5, 1, 1, 2)                               \
    QTILE(0, 1, 1, 0, t6 + 5, t6 + 6, 1, 1, 2)                               \
    QTILE(1, 2, 0, 1, t6 + 6, t6 + 7, 1, 1, 2)                               \
  }                                                                          \
  QTILE(0, 0, 1, 0, 31, 0, 1, 0, 0)  /* tile 30: stage A(31), drain all */   \
  QTILE(1, 1, 0, 0, 0, 0, 0, 0, -1)  /* tile 31: pure compute */

__global__ __launch_bounds__(512, 4) void gemm_qkv(
    const bf16* __restrict__ Ag, const bf16* __restrict__ Bg,
    bf16* __restrict__ Cg, const float* __restrict__ bias,
    bf16* __restrict__ vTp) {
  __shared__ __align__(16) bf16 smem[32768];
  bf16* As = smem;
  bf16* Bs = smem + 8192;

  // XCD-chunked bijective swizzle, 96 tiles/XCD as 3bx x 32by so the
  // B-panel slice (1.5 MiB) stays L2-resident.
  int id = (int)blockIdx.y * 12 + (int)blockIdx.x;
  int wg = (id & 7) * 96 + (id >> 3);
  int ck = wg / 96, r96 = wg % 96;
  int bx = (ck & 3) * 3 + r96 % 3;
  int by = (ck >> 2) * 32 + r96 / 3;
  long m0 = (long)by * 128, n0 = (long)bx * 256;
  const bf16* A = Ag + m0 * DD;
  const bf16* B = Bg + n0 * DD;

  int t = threadIdx.x;
  int w = t >> 6, l = t & 63;
  int wm = w >> 2, wn = w & 3;  // 2 x 4 wave grid; per-wave 64x64
  int ln = l & 15, quad = l >> 4;

  int srow = l >> 2;
  int scg = ((l & 3) ^ ((l >> 3) & 3)) * 8;
  int rdslot = (quad ^ ((ln >> 1) & 3)) * 8;
  const bf16* a_base = As + (wm * 64 + ln) * 32 + rdslot;
  const bf16* b_base = Bs + (wn * 64 + ln) * 32 + rdslot;

  f32x4 acc[4][4];
#pragma unroll
  for (int i = 0; i < 4; i++)
#pragma unroll
    for (int j = 0; j < 4; j++) acc[i][j] = f32x4{0.f, 0.f, 0.f, 0.f};

  QPROLOGUE_AND_LOOP

  __syncthreads();  // epilogue below may reuse smem as a bounce buffer

  if (n0 < 2048) {
    bf16* C = Cg + m0 * 3072 + n0;
#pragma unroll
    for (int i = 0; i < 4; i++) {
      int rb = wm * 64 + i * 16 + quad * 4;
#pragma unroll
      for (int j = 0; j < 4; j++) {
        int col = wn * 64 + j * 16 + ln;
        float bv_ = bias[n0 + col];
#pragma unroll
        for (int r = 0; r < 4; r++)
          C[(long)(rb + r) * 3072 + col] = (bf16)(acc[i][j][r] + bv_);
      }
    }
  } else {
    // V region: bounce to smem[256 d][128 s], write vT[b][d][s]
    int d0 = (int)n0 - 2048;
    int b = (int)(m0 >> 11);
    int s0 = (int)(m0 & 2047);
#pragma unroll
    for (int i = 0; i < 4; i++) {
      int sl = wm * 64 + i * 16 + quad * 4;
#pragma unroll
      for (int j = 0; j < 4; j++) {
        int d = wn * 64 + j * 16 + ln;
        float bv_ = bias[n0 + d];
#pragma unroll
        for (int r = 0; r < 4; r++)
          smem[d * 128 + ((sl + r) ^ ((d & 7) << 3))] =
              (bf16)(acc[i][j][r] + bv_);
      }
    }
    __syncthreads();
    int d = t >> 1, sh = t & 1;
    bf16* dst = vTp + (long)b * DD * SS + (long)(d0 + d) * SS + s0 + sh * 64;
#pragma unroll
    for (int c = 0; c < 8; ++c) {
      int sc = (sh * 64 + c * 8) ^ ((d & 7) << 3);
      *(bf16x8*)(dst + c * 8) = *(const bf16x8*)(smem + d * 128 + sc);
    }
  }
}

// =====================================================================
// scores256: causal scores + fused exp on the QTILE structure.
// A = q rows [m0,m0+128), B = k rows [n0,n0+256), both from qkv (ld 3072).
// Triangular 256-col grid: 72 tiles/batch, closed-form decode.
// Epilogue: P~ = exp(acc/32) (0 above diag) -> full-smem bounce (chunk-XOR
// row&7 swizzle) -> vectorized copy-out; rowsums from bf16-rounded P~
// (4-thread shfl combine -> 1 atomicAdd per row).
// =====================================================================
#define CSTGA(pa, kt)                                                        \
  gload_lds16(Aq + (long)(w * 16 + srow) * 3072 + (kt) * 32 + scg,           \
              As + (pa) * 4096 + w * 512)
#define CSTGB(pb, h, kt)                                                     \
  gload_lds16(Bk + (long)((h) * 128 + w * 16 + srow) * 3072 + (kt) * 32 +    \
                  scg,                                                       \
              Bs + (pb) * 8192 + (h) * 4096 + w * 512)

#define CTILE(pa, pb, pa1, pb2, kA, kB, DOA, DOB, WAITN)                     \
  {                                                                          \
    bf16x8 af[4], bfr[4];                                                    \
    _Pragma("unroll") for (int i_ = 0; i_ < 4; i_++)                         \
        af[i_] = *(const bf16x8*)(a_base + (pa) * 4096 + i_ * 512);          \
    _Pragma("unroll") for (int j_ = 0; j_ < 4; j_++)                         \
        bfr[j_] = *(const bf16x8*)(b_base + (pb) * 8192 + j_ * 512);         \
    if (DOA) { CSTGA(pa1, kA); }                                             \
    if (DOB) { CSTGB(pb2, 0, kB); CSTGB(pb2, 1, kB); }                       \
    __builtin_amdgcn_s_barrier();                                            \
    asm volatile("s_waitcnt lgkmcnt(0)" ::: "memory");                       \
    __builtin_amdgcn_sched_barrier(0);                                       \
    __builtin_amdgcn_s_setprio(1);                                           \
    _Pragma("unroll") for (int i_ = 0; i_ < 4; i_++)                         \
        _Pragma("unroll") for (int j_ = 0; j_ < 4; j_++) acc[i_][j_] =       \
        __builtin_amdgcn_mfma_f32_16x16x32_bf16(af[i_], bfr[j_],             \
                                                acc[i_][j_], 0, 0, 0);       \
    __builtin_amdgcn_s_setprio(0);                                           \
    __builtin_amdgcn_sched_barrier(0);                                       \
    if ((WAITN) == 2) asm volatile("s_waitcnt vmcnt(2)" ::: "memory");       \
    if ((WAITN) == 0) asm volatile("s_waitcnt vmcnt(0)" ::: "memory");       \
    __builtin_amdgcn_s_barrier();                                            \
    __builtin_amdgcn_sched_barrier(0);                                       \
  }

__global__ __launch_bounds__(512, 4) void scores256(
    const bf16* __restrict__ qkvp, bf16* __restrict__ P,
    float* __restrict__ rowsums) {
  __shared__ __align__(16) bf16 smem[32768];
  bf16* As = smem;
  bf16* Bs = smem + 8192;

  int bz = blockIdx.z;
  // XCD swizzle over 72 (72 % 8 == 0 -> simple chunked form is bijective)
  int id = (int)blockIdx.x;
  int q = (id & 7) * 9 + (id >> 3);
  // triangular decode at 256-col granularity:
  // T(2m)=m(m+1), T(2m+1)=(m+1)^2; q in [T(by), T(by+1)) -> (by, bxc)
  int s = (int)sqrtf((float)q + 0.5f);
  while (s * s > q) s--;
  while ((s + 1) * (s + 1) <= q) s++;
  int by, bxc;
  if (q >= s * (s + 1)) { by = 2 * s; bxc = q - s * (s + 1); }
  else { by = 2 * s - 1; bxc = q - s * s; }
  long m0 = (long)by * 128, n0 = (long)bxc * 256;
  const bf16* Aq = qkvp + (long)bz * SS * 3072 + m0 * 3072;
  const bf16* Bk = qkvp + 1024 + (long)bz * SS * 3072 + n0 * 3072;

  int t = threadIdx.x;
  int w = t >> 6, l = t & 63;
  int wm = w >> 2, wn = w & 3;
  int ln = l & 15, quad = l >> 4;

  int srow = l >> 2;
  int scg = ((l & 3) ^ ((l >> 3) & 3)) * 8;
  int rdslot = (quad ^ ((ln >> 1) & 3)) * 8;
  const bf16* a_base = As + (wm * 64 + ln) * 32 + rdslot;
  const bf16* b_base = Bs + (wn * 64 + ln) * 32 + rdslot;

  f32x4 acc[4][4];
#pragma unroll
  for (int i = 0; i < 4; i++)
#pragma unroll
    for (int j = 0; j < 4; j++) acc[i][j] = f32x4{0.f, 0.f, 0.f, 0.f};

  // prologue + 32 K-tiles (identical schedule to gemm_qkv)
  CSTGA(0, 0);
  CSTGB(0, 0, 0); CSTGB(0, 1, 0);
  CSTGB(1, 0, 1); CSTGB(1, 1, 1);
  asm volatile("s_waitcnt vmcnt(2)" ::: "memory");
  __builtin_amdgcn_s_barrier();
  __builtin_amdgcn_sched_barrier(0);
#pragma unroll 1
  for (int t6 = 0; t6 < 30; t6 += 6) {
    CTILE(0, 0, 1, 2, t6 + 1, t6 + 2, 1, 1, 2)
    CTILE(1, 1, 0, 0, t6 + 2, t6 + 3, 1, 1, 2)
    CTILE(0, 2, 1, 1, t6 + 3, t6 + 4, 1, 1, 2)
    CTILE(1, 0, 0, 2, t6 + 4, t6 + 5, 1, 1, 2)
    CTILE(0, 1, 1, 0, t6 + 5, t6 + 6, 1, 1, 2)
    CTILE(1, 2, 0, 1, t6 + 6, t6 + 7, 1, 1, 2)
  }
  CTILE(0, 0, 1, 0, 31, 0, 1, 0, 0)
  CTILE(1, 1, 0, 0, 0, 0, 0, 0, -1)

  __syncthreads();  // reuse ALL of smem as the 128x256 bf16 bounce buffer

  // exp epilogue -> smem[row*256 + (col ^ ((row&7)<<3))] (16B-chunk XOR)
#pragma unroll
  for (int i = 0; i < 4; i++) {
    int rb = wm * 64 + i * 16 + quad * 4;
#pragma unroll
    for (int j = 0; j < 4; j++) {
      int col = wn * 64 + j * 16 + ln;
#pragma unroll
      for (int r = 0; r < 4; r++) {
        int row = rb + r;
        float p = 0.f;
        if (n0 + col <= m0 + row) p = __expf(acc[i][j][r] * 0.03125f);
        smem[row * 256 + (col ^ ((row & 7) << 3))] = (bf16)p;
      }
    }
  }
  __syncthreads();
  // copy-out: thread -> (row t>>2, 64-col quarter t&3); rowsum of
  // bf16-rounded P~ combined across the 4 quarter-threads (same wave).
  int row = t >> 2, qtr = t & 3;
  bf16* Pr = P + (long)bz * SS * SS + (m0 + row) * SS + n0;
  float rsum = 0.f;
#pragma unroll
  for (int c8 = 0; c8 < 8; c8++) {
    int p8 = qtr * 8 + c8;
    int slot = p8 ^ (row & 7);
    bf16x8 v = *(const bf16x8*)(smem + row * 256 + slot * 8);
#pragma unroll
    for (int e = 0; e < 8; e++) rsum += (float)v[e];
    *(bf16x8*)(Pr + p8 * 8) = v;
  }
  rsum += __shfl_xor(rsum, 1, 64);
  rsum += __shfl_xor(rsum, 2, 64);
  if (qtr == 0) atomicAdd(&rowsums[(long)bz * SS + m0 + row], rsum);
}

// ---- generic bf16 GEMM: 128x128 tiles (fold / PV) ----------------------
// MODE 0: C bf16 (+bias).
// MODE 2: P~ @ V with causal K truncation; epilogue divides by rowsums.
template <int MODE>
__global__ __launch_bounds__(256, 4)
void gemm_bt(const bf16* __restrict__ Ag, long lda, long sAb,
             const bf16* __restrict__ Bg, long ldb, long sBb,
             void* __restrict__ Cg, long ldc, long sCb,
             const float* __restrict__ bias, float scale, int K,
             bf16* __restrict__ vTp, float* __restrict__ rowsums) {
  __shared__ __align__(16) bf16 smem[16384];  // As | Bs
  bf16* As = smem;
  bf16* Bs = smem + 8192;

  int bx = blockIdx.x, by = blockIdx.y, bz = blockIdx.z;
  if (MODE == 0) {
    int nx = (int)gridDim.x;
    int nwg = nx * (int)gridDim.y;
    int id = by * nx + bx;
    int xcd = id & 7, rest = id >> 3;
    int q8 = nwg >> 3, r8 = nwg & 7;
    int wg = (xcd < r8 ? xcd * (q8 + 1) : r8 * (q8 + 1) + (xcd - r8) * q8)
             + rest;
    bx = wg % nx;
    by = wg / nx;
  }
  if (MODE == 2) by = 15 - by;  // longest K strips dispatch first
  long m0 = (long)by * 128, n0 = (long)bx * 128;
  const bf16* A = Ag + (long)bz * sAb + m0 * lda;
  const bf16* Bp = Bg + (long)bz * sBb + n0 * ldb;

  int t = threadIdx.x;
  int w = t >> 6, l = t & 63;
  int lr = l >> 2;
  int lc = (((l & 3) ^ (lr & 3)) * 8);  // swizzled source chunk
  int quad = l >> 4, ln = l & 15;
  int wm = w >> 1, wn = w & 1;
  int rdoff = ((quad ^ (ln & 3)) * 8);  // swizzled read offset

  int Keff = (MODE == 2) ? (by + 1) * 128 : K;

  f32x4 acc[4][4];
#pragma unroll
  for (int i = 0; i < 4; i++)
#pragma unroll
    for (int j = 0; j < 4; j++) acc[i][j] = f32x4{0.f, 0.f, 0.f, 0.f};

  const bf16* a_base = As + (wm * 64 + ln) * 32 + rdoff;
  const bf16* b_base = Bs + (wn * 64 + ln) * 32 + rdoff;
  long arow0 = (long)(w * 16 + lr);

#define STG(p, kc0)                                                         \
  {                                                                         \
    int kc = (kc0) + lc;                                                    \
    gload_lds16(A + arow0 * lda + kc, As + (p) * 4096 + w * 512);           \
    gload_lds16(A + (arow0 + 64) * lda + kc,                                \
                As + (p) * 4096 + 2048 + w * 512);                          \
    gload_lds16(Bp + arow0 * ldb + kc, Bs + (p) * 4096 + w * 512);          \
    gload_lds16(Bp + (arow0 + 64) * ldb + kc,                               \
                Bs + (p) * 4096 + 2048 + w * 512);                          \
  }

  STG(0, 0);
  int cur = 0;
  for (int k = 0; k < Keff; k += 32) {
    asm volatile("s_waitcnt vmcnt(0)" ::: "memory");
    __builtin_amdgcn_s_barrier();
    __builtin_amdgcn_sched_barrier(0);
    if (k + 32 < Keff) STG(cur ^ 1, k + 32);
    bf16x8 af[4], bfr[4];
#pragma unroll
    for (int i = 0; i < 4; i++) {
      af[i] = *(const bf16x8*)(a_base + cur * 4096 + i * 512);
      bfr[i] = *(const bf16x8*)(b_base + cur * 4096 + i * 512);
    }
#pragma unroll
    for (int i = 0; i < 4; i++)
#pragma unroll
      for (int j = 0; j < 4; j++)
        acc[i][j] = __builtin_amdgcn_mfma_f32_16x16x32_bf16(
            af[i], bfr[j], acc[i][j], 0, 0, 0);
    cur ^= 1;
  }
#undef STG
  __syncthreads();

  if (MODE == 0) {
    bf16* C = (bf16*)Cg + (long)bz * sCb + m0 * ldc + n0;
#pragma unroll
    for (int i = 0; i < 4; i++) {
      int rb = wm * 64 + i * 16 + quad * 4;
#pragma unroll
      for (int j = 0; j < 4; j++) {
        int col = wn * 64 + j * 16 + ln;
        float bv_ = bias ? bias[n0 + col] : 0.f;
#pragma unroll
        for (int r = 0; r < 4; r++)
          C[(long)(rb + r) * ldc + col] = (bf16)(acc[i][j][r] + bv_);
      }
    }
  } else {
    float* C = (float*)Cg + (long)bz * sCb + m0 * ldc + n0;
    const float* rs = rowsums + (long)bz * SS + m0;
#pragma unroll
    for (int i = 0; i < 4; i++) {
      int rb = wm * 64 + i * 16 + quad * 4;
      float inv[4];
#pragma unroll
      for (int r = 0; r < 4; r++) inv[r] = 1.f / rs[rb + r];
#pragma unroll
      for (int j = 0; j < 4; j++) {
        int col = wn * 64 + j * 16 + ln;
#pragma unroll
        for (int r = 0; r < 4; r++)
          C[(long)(rb + r) * ldc + col] = acc[i][j][r] * inv[r];
      }
    }
  }
}

extern "C" void kernel_launch(void* const* d_in, const int* in_sizes, int n_in,
                              void* d_out, int out_size, void* d_ws,
                              size_t ws_size, hipStream_t stream) {
  const float* x = (const float*)d_in[0];
  const float* R = (const float*)d_in[1];
  const float* E = (const float*)d_in[2];
  const float* Wq = (const float*)d_in[3];
  const float* bq = (const float*)d_in[4];
  const float* Wk = (const float*)d_in[5];
  const float* bk = (const float*)d_in[6];
  const float* Wv = (const float*)d_in[7];
  const float* bv = (const float*)d_in[8];
  float* out = (float*)d_out;

  char* ws = (char*)d_ws;
  bf16* qkv = (bf16*)ws;
  bf16* vT = (bf16*)(ws + 50331648);
  bf16* probs = (bf16*)(ws + 67108864);
  float* rowsums = (float*)(ws + 100663296);
  char* sr = ws + 101711872;
  bf16* xb = (bf16*)sr;                   // 16 MiB
  bf16* Rb = (bf16*)(sr + 16777216);      // 2 MiB
  bf16* Eb = Rb + 1024 * 1024;            // 2 MiB
  bf16* WqT = (bf16*)(sr + 20971520);     // 2 MiB
  bf16* WkT = WqT + 1024 * 1024;          // 2 MiB
  bf16* wcat = (bf16*)(sr + 25165824);    // 6 MiB (Wq'|Wk'|Wv)
  float* bias = (float*)(sr + 31457280);  // 12 KiB

  // 1) all preprocessing + rowsum zeroing: 1 dispatch
  prep_all<<<16416, 256, 0, stream>>>(x, R, E, Wv, Wq, Wk, bq, bk, bv, xb, Rb,
                                      Eb, wcat + 2048 * DD, WqT, WkT, bias,
                                      rowsums);

  // 2) fold weights (batched bz=2): Wq' = R@Wq ; Wk' = E@Wk
  gemm_bt<0><<<dim3(8, 8, 2), 256, 0, stream>>>(
      Rb, DD, 1024 * 1024, WqT, DD, 1024 * 1024, wcat, DD, 1024 * 1024,
      nullptr, 1.f, DD, nullptr, nullptr);

  // 3) fused QKV (M=8192, N=3072, K=1024), 128x256 tiles, 768 blocks;
  //    V-tiles written transposed to vT
  gemm_qkv<<<dim3(12, 64, 1), 512, 0, stream>>>(xb, wcat, qkv, bias, vT);

  // 4) causal scores + fused exp -> bf16 probs + row sums
  //    (288 triangular 128x256 tiles on the QTILE structure)
  scores256<<<dim3(72, 1, BB), 512, 0, stream>>>(qkv, probs, rowsums);

  // 5) out = (P~ @ V) / rowsum : K truncated causally, long strips first
  gemm_bt<2><<<dim3(8, 16, BB), 256, 0, stream>>>(
      probs, SS, (long)SS * SS, vT, SS, (long)DD * SS, out,
      DD, (long)SS * DD, nullptr, 1.f, SS, nullptr, rowsums);
}